// Round 6
// baseline (193.634 us; speedup 1.0000x reference)
//
#include <hip/hip_runtime.h>
#include <math.h>

#define NV   6890
#define NJ   24
#define NB   10
#define NPF  207
#define NCJ  19
#define BATCHN 1024
#define NC3  (NV*3)     // 20670
#define KTOT 224        // 207 pose + 10 beta + 7 zero pad

#define OUT_JOINTS_OFF (BATCHN*NV*3)
#define OUT_RS_OFF     (OUT_JOINTS_OFF + BATCHN*NCJ*3)

// ws float offsets
#define WS_JS     0        // [24][33] f32
#define WS_EF     1024     // [1024][224] bf16 (ushort)
#define WS_AADJT  115712   // [1024][16][32] bf16 (ushort)
#define WS_DIRST  377856   // [216][7][6][16][32] bf16 (ushort)
#define DIRST_FLOATS 2322432

typedef __attribute__((ext_vector_type(8))) short short8;
typedef __attribute__((ext_vector_type(4))) float f32x4;

__device__ __forceinline__ unsigned short f2bf(float f) {
    unsigned u = __float_as_uint(f);
    unsigned r = u + 0x7FFFu + ((u >> 16) & 1u);   // RNE
    return (unsigned short)(r >> 16);
}

// ---------------- Kernel A: fold J_regressor into shapedirs/v_template ----
__global__ void smpl_kA(const float* __restrict__ jreg, const float* __restrict__ sdirs,
                        const float* __restrict__ vtmpl, float* __restrict__ js) {
    int j = blockIdx.x;
    int tid = threadIdx.x;  // 256
    float acc[33];
#pragma unroll
    for (int e = 0; e < 33; e++) acc[e] = 0.f;
    for (int v = tid; v < NV; v += 256) {
        float w = jreg[j * NV + v];
#pragma unroll
        for (int k = 0; k < NB; k++) {
#pragma unroll
            for (int d = 0; d < 3; d++)
                acc[k * 3 + d] += w * sdirs[(size_t)k * NC3 + v * 3 + d];
        }
#pragma unroll
        for (int d = 0; d < 3; d++) acc[30 + d] += w * vtmpl[v * 3 + d];
    }
#pragma unroll
    for (int e = 0; e < 33; e++) {
#pragma unroll
        for (int off = 32; off >= 1; off >>= 1) acc[e] += __shfl_xor(acc[e], off, 64);
    }
    __shared__ float red[4][33];
    int lane = tid & 63, wv = tid >> 6;
    if (lane == 0) {
#pragma unroll
        for (int e = 0; e < 33; e++) red[wv][e] = acc[e];
    }
    __syncthreads();
    if (tid < 33) js[j * 33 + tid] = red[0][tid] + red[1][tid] + red[2][tid] + red[3][tid];
}

// ---------------- Kernel P: dirs -> bf16 fragment-major (LDS transpose) ---
// dirsT[vt][ks][s][c(16)][k(32)]; frag (ks,s) is 1KB contiguous.
__global__ __launch_bounds__(256) void smpl_kP(
    const float* __restrict__ pdirs, const float* __restrict__ sdirs,
    unsigned short* __restrict__ dirsT) {
    __shared__ unsigned short tile[21504];   // 42KB
    int vt = blockIdx.x, tid = threadIdx.x;
    for (int e = tid; e < KTOT * 96; e += 256) {
        int k = e / 96, c = e - k * 96;
        int gc = vt * 96 + c;
        float val = 0.f;
        if (gc < NC3) {
            if (k < NPF) val = pdirs[(size_t)k * NC3 + gc];
            else if (k < NPF + NB) val = sdirs[(size_t)(k - NPF) * NC3 + gc];
        }
        tile[(((k >> 5) * 6 + (c >> 4)) << 9) + ((c & 15) << 5) + (k & 31)] = f2bf(val);
    }
    __syncthreads();
    const unsigned int* t32 = (const unsigned int*)tile;
    unsigned int* d32 = (unsigned int*)(dirsT + (size_t)vt * 21504);
    for (int e = tid; e < 21504 / 2; e += 256) d32[e] = t32[e];
}

// ---------------- Kernel B: Rodrigues + chain + bf16 packs ----------------
__global__ void smpl_kB(const float* __restrict__ theta, const float* __restrict__ beta_,
                        const float* __restrict__ js, float* __restrict__ outRs,
                        unsigned short* __restrict__ ef, unsigned short* __restrict__ aadjT) {
    int b = blockIdx.x;
    int t = threadIdx.x;  // 64
    __shared__ float Rl[NJ][9];
    __shared__ float Jl[NJ][3];
    __shared__ float Rw[NJ][12];

    if (t < NJ) {
        int j = t;
        float tx = theta[b * 72 + j * 3 + 0];
        float ty = theta[b * 72 + j * 3 + 1];
        float tz = theta[b * 72 + j * 3 + 2];
        float ax = tx + 1e-8f, ay = ty + 1e-8f, az = tz + 1e-8f;
        float ang = sqrtf(ax * ax + ay * ay + az * az);
        float inv = 1.0f / ang;
        float rx = tx * inv, ry = ty * inv, rz = tz * inv;
        float s = sinf(ang), c = cosf(ang), t1 = 1.0f - c;
        float R[9];
        R[0] = 1.0f - t1 * (ry * ry + rz * rz);
        R[1] = -s * rz + t1 * rx * ry;
        R[2] =  s * ry + t1 * rx * rz;
        R[3] =  s * rz + t1 * rx * ry;
        R[4] = 1.0f - t1 * (rx * rx + rz * rz);
        R[5] = -s * rx + t1 * ry * rz;
        R[6] = -s * ry + t1 * rx * rz;
        R[7] =  s * rx + t1 * ry * rz;
        R[8] = 1.0f - t1 * (rx * rx + ry * ry);
#pragma unroll
        for (int e = 0; e < 9; e++) {
            Rl[j][e] = R[e];
            outRs[(size_t)b * 216 + j * 9 + e] = R[e];
        }
#pragma unroll
        for (int d = 0; d < 3; d++) {
            float accJ = js[j * 33 + 30 + d];
#pragma unroll
            for (int k = 0; k < NB; k++) accJ += beta_[b * NB + k] * js[j * 33 + k * 3 + d];
            Jl[j][d] = accJ;
        }
    }
    __syncthreads();
    for (int e = t; e < KTOT; e += 64) {
        float val;
        if (e < NPF) {
            int j = e / 9 + 1;
            int rc = e - (j - 1) * 9;
            val = Rl[j][rc] - ((rc == 0 || rc == 4 || rc == 8) ? 1.0f : 0.0f);
        } else if (e < NPF + NB) {
            val = beta_[b * NB + (e - NPF)];
        } else val = 0.f;
        ef[(size_t)b * KTOT + e] = f2bf(val);
    }
    if (t == 0) {
#pragma unroll
        for (int r = 0; r < 3; r++) {
            Rw[0][r * 4 + 0] =  Rl[0][r * 3 + 0];
            Rw[0][r * 4 + 1] = -Rl[0][r * 3 + 1];
            Rw[0][r * 4 + 2] = -Rl[0][r * 3 + 2];
            Rw[0][r * 4 + 3] =  Jl[0][r];
        }
        const int par[NJ] = {0,0,0,0,1,2,3,4,5,6,7,8,9,9,9,12,13,14,16,17,18,19,20,21};
#pragma unroll
        for (int i = 1; i < NJ; i++) {
            int p = par[i];
            float tr0 = Jl[i][0] - Jl[p][0];
            float tr1 = Jl[i][1] - Jl[p][1];
            float tr2 = Jl[i][2] - Jl[p][2];
#pragma unroll
            for (int r = 0; r < 3; r++) {
                float p0 = Rw[p][r * 4 + 0], p1 = Rw[p][r * 4 + 1], p2 = Rw[p][r * 4 + 2];
#pragma unroll
                for (int cc = 0; cc < 3; cc++)
                    Rw[i][r * 4 + cc] = p0 * Rl[i][0 + cc] + p1 * Rl[i][3 + cc] + p2 * Rl[i][6 + cc];
                Rw[i][r * 4 + 3] = p0 * tr0 + p1 * tr1 + p2 * tr2 + Rw[p][r * 4 + 3];
            }
        }
    }
    __syncthreads();
    for (int i = t; i < 512; i += 64) {
        int n = i >> 5, k = i & 31;
        float v = 0.f;
        if (n < 12 && k < 24) {
            int r = n >> 2, cc = n & 3;
            if (cc < 3) v = Rw[k][n];
            else v = Rw[k][r * 4 + 3] - (Rw[k][r * 4 + 0] * Jl[k][0] + Rw[k][r * 4 + 1] * Jl[k][1] +
                                         Rw[k][r * 4 + 2] * Jl[k][2]);
        }
        aadjT[(size_t)b * 512 + i] = f2bf(v);
    }
}

// ---------------- Kernel C3: pipelined L2-dirs MFMA GEMM + MFMA T-blend ---
__global__ __launch_bounds__(256, 4) void smpl_kC3(
    const unsigned short* __restrict__ dirsT, const float* __restrict__ vtmpl,
    const unsigned short* __restrict__ ef, const unsigned short* __restrict__ aadjT,
    const float* __restrict__ wts, float* __restrict__ outv) {
    __shared__ float vph[3 * 2113];            // v_posed [d][v*66 + b]
    __shared__ unsigned short wbf[32][32];     // weights bf16 [v][k]

    int tid = threadIdx.x;
    int vtile = blockIdx.x;
    int btile = blockIdx.y * 64;
    int lane = tid & 63, wv = tid >> 6;
    int l15 = lane & 15, lg = lane >> 4;

    for (int e = tid; e < 32 * 32; e += 256) {
        int vl = e >> 5, k = e & 31;
        int gv = vtile * 32 + vl;
        float w = (k < NJ && gv < NV) ? wts[(size_t)gv * NJ + k] : 0.f;
        wbf[vl][k] = f2bf(w);
    }
    __syncthreads();

    short8 wf0 = *(const short8*)&wbf[l15][lg * 8];
    short8 wf1 = *(const short8*)&wbf[16 + l15][lg * 8];
    float vt[6];
#pragma unroll
    for (int s = 0; s < 6; s++) {
        int gcol = vtile * 96 + s * 16 + l15;
        vt[s] = (gcol < NC3) ? vtmpl[gcol] : 0.f;
    }

    // ---- pose+shape GEMM, software-pipelined 2-deep ----
    const short8* efr = (const short8*)(ef + (size_t)(btile + wv * 16 + l15) * KTOT);
    const short8* bfr = (const short8*)(dirsT + (size_t)vtile * (7 * 6 * 512));
    int fo = l15 * 4 + lg;
    // A-fragments all resident
    short8 av[7];
#pragma unroll
    for (int ks = 0; ks < 7; ks++) av[ks] = efr[ks * 4 + lg];
    // B double buffer
    short8 bcur[6], bnxt[6];
#pragma unroll
    for (int s = 0; s < 6; s++) bcur[s] = bfr[s * 64 + fo];
    f32x4 acc[6];
#pragma unroll
    for (int s = 0; s < 6; s++) acc[s] = (f32x4){0.f, 0.f, 0.f, 0.f};
#pragma unroll
    for (int ks = 0; ks < 7; ks++) {
        if (ks < 6) {
#pragma unroll
            for (int s = 0; s < 6; s++) bnxt[s] = bfr[((ks + 1) * 6 + s) * 64 + fo];
        }
#pragma unroll
        for (int s = 0; s < 6; s++)
            acc[s] = __builtin_amdgcn_mfma_f32_16x16x32_bf16(av[ks], bcur[s], acc[s], 0, 0, 0);
#pragma unroll
        for (int s = 0; s < 6; s++) bcur[s] = bnxt[s];
    }
    // ---- epilogue: vph = acc + v_template (wave-local batches, no barrier)
#pragma unroll
    for (int s = 0; s < 6; s++) {
        int col = s * 16 + l15;
        int v = col / 3, d = col - v * 3;
#pragma unroll
        for (int r = 0; r < 4; r++) {
            int bl = wv * 16 + lg * 4 + r;
            vph[d * 2113 + v * 66 + bl] = acc[s][r] + vt[s];
        }
    }
    // ---- skinning: per-batch MFMA T-blend, 2-deep prefetch ----
    const short8* at0 = (const short8*)(aadjT + (size_t)(btile + wv * 16) * 512);
    short8 af0 = at0[fo];
    short8 af1 = at0[64 + fo];
#pragma unroll
    for (int bl2 = 0; bl2 < 16; bl2++) {
        short8 af = af0;
        af0 = af1;
        if (bl2 < 14) af1 = at0[(bl2 + 2) * 64 + fo];
        f32x4 z = (f32x4){0.f, 0.f, 0.f, 0.f};
        f32x4 t0 = __builtin_amdgcn_mfma_f32_16x16x32_bf16(af, wf0, z, 0, 0, 0);
        f32x4 t1 = __builtin_amdgcn_mfma_f32_16x16x32_bf16(af, wf1, z, 0, 0, 0);
        int b = btile + wv * 16 + bl2;
        int wvb = wv * 16 + bl2;
        if (lg < 3) {
            int p = lg;
            {
                int vv = l15;
                float x0 = vph[0 * 2113 + vv * 66 + wvb];
                float x1 = vph[1 * 2113 + vv * 66 + wvb];
                float x2 = vph[2 * 2113 + vv * 66 + wvb];
                float o = fmaf(t0[0], x0, fmaf(t0[1], x1, fmaf(t0[2], x2, t0[3])));
                int gv = vtile * 32 + vv;
                if (gv < NV) outv[(size_t)b * NC3 + gv * 3 + p] = o;
            }
            {
                int vv = 16 + l15;
                float x0 = vph[0 * 2113 + vv * 66 + wvb];
                float x1 = vph[1 * 2113 + vv * 66 + wvb];
                float x2 = vph[2 * 2113 + vv * 66 + wvb];
                float o = fmaf(t1[0], x0, fmaf(t1[1], x1, fmaf(t1[2], x2, t1[3])));
                int gv = vtile * 32 + vv;
                if (gv < NV) outv[(size_t)b * NC3 + gv * 3 + p] = o;
            }
        }
    }
}

// ---------------- Kernel C (fallback, LDS-resident dirs) ------------------
__global__ __launch_bounds__(256, 2) void smpl_kC(
    const float* __restrict__ pdirs, const float* __restrict__ sdirs,
    const float* __restrict__ vtmpl, const unsigned short* __restrict__ ef,
    const unsigned short* __restrict__ aadjT, const float* __restrict__ wts,
    float* __restrict__ outv) {
    __shared__ unsigned short dlds[96][232];
    __shared__ float vph[3 * 2113];
    __shared__ unsigned short wbf[32][32];

    int tid = threadIdx.x;
    int vtile = blockIdx.x;
    int lane = tid & 63, wv = tid >> 6;
    int l15 = lane & 15, lg = lane >> 4;

    for (int e = tid; e < KTOT * 96; e += 256) {
        int k = e / 96, c = e - k * 96;
        int gc = vtile * 96 + c;
        float val = 0.f;
        if (gc < NC3) {
            if (k < NPF) val = pdirs[(size_t)k * NC3 + gc];
            else if (k < NPF + NB) val = sdirs[(size_t)(k - NPF) * NC3 + gc];
        }
        dlds[c][k] = f2bf(val);
    }
    for (int e = tid; e < 32 * 32; e += 256) {
        int vl = e >> 5, k = e & 31;
        int gv = vtile * 32 + vl;
        float w = (k < NJ && gv < NV) ? wts[(size_t)gv * NJ + k] : 0.f;
        wbf[vl][k] = f2bf(w);
    }
    __syncthreads();

    short8 wf0 = *(const short8*)&wbf[l15][lg * 8];
    short8 wf1 = *(const short8*)&wbf[16 + l15][lg * 8];
    float vt[6];
#pragma unroll
    for (int s = 0; s < 6; s++) {
        int gcol = vtile * 96 + s * 16 + l15;
        vt[s] = (gcol < NC3) ? vtmpl[gcol] : 0.f;
    }

    for (int bt = 0; bt < 8; bt++) {
        int btile = (blockIdx.y * 8 + bt) * 64;
        const short8* efr = (const short8*)(ef + (size_t)(btile + wv * 16 + l15) * KTOT);
        f32x4 acc[6];
#pragma unroll
        for (int s = 0; s < 6; s++) acc[s] = (f32x4){0.f, 0.f, 0.f, 0.f};
#pragma unroll
        for (int ks = 0; ks < 7; ks++) {
            short8 av = efr[ks * 4 + lg];
#pragma unroll
            for (int s = 0; s < 6; s++) {
                short8 bv = *(const short8*)&dlds[s * 16 + l15][ks * 32 + lg * 8];
                acc[s] = __builtin_amdgcn_mfma_f32_16x16x32_bf16(av, bv, acc[s], 0, 0, 0);
            }
        }
#pragma unroll
        for (int s = 0; s < 6; s++) {
            int col = s * 16 + l15;
            int v = col / 3, d = col - v * 3;
#pragma unroll
            for (int r = 0; r < 4; r++) {
                int bl = wv * 16 + lg * 4 + r;
                vph[d * 2113 + v * 66 + bl] = acc[s][r] + vt[s];
            }
        }
        const short8* at0 = (const short8*)(aadjT + (size_t)(btile + wv * 16) * 512);
        short8 afn = at0[l15 * 4 + lg];
#pragma unroll
        for (int bl2 = 0; bl2 < 16; bl2++) {
            short8 af = afn;
            if (bl2 < 15) afn = at0[(bl2 + 1) * 64 + l15 * 4 + lg];
            f32x4 z = (f32x4){0.f, 0.f, 0.f, 0.f};
            f32x4 t0 = __builtin_amdgcn_mfma_f32_16x16x32_bf16(af, wf0, z, 0, 0, 0);
            f32x4 t1 = __builtin_amdgcn_mfma_f32_16x16x32_bf16(af, wf1, z, 0, 0, 0);
            int b = btile + wv * 16 + bl2;
            int wvb = wv * 16 + bl2;
            if (lg < 3) {
                int p = lg;
                {
                    int vv = l15;
                    float x0 = vph[0 * 2113 + vv * 66 + wvb];
                    float x1 = vph[1 * 2113 + vv * 66 + wvb];
                    float x2 = vph[2 * 2113 + vv * 66 + wvb];
                    float o = fmaf(t0[0], x0, fmaf(t0[1], x1, fmaf(t0[2], x2, t0[3])));
                    int gv = vtile * 32 + vv;
                    if (gv < NV) outv[(size_t)b * NC3 + gv * 3 + p] = o;
                }
                {
                    int vv = 16 + l15;
                    float x0 = vph[0 * 2113 + vv * 66 + wvb];
                    float x1 = vph[1 * 2113 + vv * 66 + wvb];
                    float x2 = vph[2 * 2113 + vv * 66 + wvb];
                    float o = fmaf(t1[0], x0, fmaf(t1[1], x1, fmaf(t1[2], x2, t1[3])));
                    int gv = vtile * 32 + vv;
                    if (gv < NV) outv[(size_t)b * NC3 + gv * 3 + p] = o;
                }
            }
        }
    }
}

// ---------------- Kernel D: COCO joint regression, 1 batch/wave -----------
// 256 blocks x 256 threads; block = 4 batches (one per wave); jr shared via L1/L2.
__global__ __launch_bounds__(256) void smpl_kD(
    const float* __restrict__ verts, const float* __restrict__ jr,
    float* __restrict__ outj) {
    int wv = threadIdx.x >> 6, lane = threadIdx.x & 63;
    int b = blockIdx.x * 4 + wv;
    const float* vb = verts + (size_t)b * NC3;
    float acc[57];
#pragma unroll
    for (int e = 0; e < 57; e++) acc[e] = 0.f;

    for (int it = 0; it < 54; it++) {
        int v2 = it * 64 + lane;     // vert-pair index, 3445 pairs
        if (v2 < 3445) {
            int v = v2 * 2;
            const float* pa = vb + v * 3;
            float2 a0 = *(const float2*)(pa);      // x0 y0
            float2 a1 = *(const float2*)(pa + 2);  // z0 x1
            float2 a2 = *(const float2*)(pa + 4);  // y1 z1
#pragma unroll
            for (int j = 0; j < NCJ; j++) {
                float2 w = *(const float2*)(jr + (size_t)j * NV + v);
                acc[j * 3 + 0] = fmaf(w.x, a0.x, fmaf(w.y, a1.y, acc[j * 3 + 0]));
                acc[j * 3 + 1] = fmaf(w.x, a0.y, fmaf(w.y, a2.x, acc[j * 3 + 1]));
                acc[j * 3 + 2] = fmaf(w.x, a1.x, fmaf(w.y, a2.y, acc[j * 3 + 2]));
            }
        }
    }
#pragma unroll
    for (int e = 0; e < 57; e++) {
#pragma unroll
        for (int off = 32; off >= 1; off >>= 1) acc[e] += __shfl_xor(acc[e], off, 64);
    }
    if (lane == 0) {
#pragma unroll
        for (int e = 0; e < 57; e++) outj[(size_t)b * 57 + e] = acc[e];
    }
}

extern "C" void kernel_launch(void* const* d_in, const int* in_sizes, int n_in,
                              void* d_out, int out_size, void* d_ws, size_t ws_size,
                              hipStream_t stream) {
    (void)in_sizes; (void)n_in; (void)out_size;
    const float* beta       = (const float*)d_in[0];
    const float* theta      = (const float*)d_in[1];
    const float* v_template = (const float*)d_in[2];
    const float* shapedirs  = (const float*)d_in[3];
    const float* jreg       = (const float*)d_in[4];
    const float* posedirs   = (const float*)d_in[5];
    const float* jointreg   = (const float*)d_in[6];
    const float* weights    = (const float*)d_in[7];
    float* out = (float*)d_out;
    float* ws  = (float*)d_ws;
    unsigned short* ef    = (unsigned short*)(ws + WS_EF);
    unsigned short* aadjT = (unsigned short*)(ws + WS_AADJT);
    unsigned short* dirsT = (unsigned short*)(ws + WS_DIRST);
    bool bigws = ws_size >= (size_t)(WS_DIRST + DIRST_FLOATS) * sizeof(float);

    smpl_kA<<<NJ, 256, 0, stream>>>(jreg, shapedirs, v_template, ws + WS_JS);
    smpl_kB<<<BATCHN, 64, 0, stream>>>(theta, beta, ws + WS_JS, out + OUT_RS_OFF,
                                       ef, aadjT);
    if (bigws) {
        smpl_kP<<<216, 256, 0, stream>>>(posedirs, shapedirs, dirsT);
        dim3 gC(216, 16);
        smpl_kC3<<<gC, 256, 0, stream>>>(dirsT, v_template, ef, aadjT, weights, out);
    } else {
        dim3 gC(216, 2);
        smpl_kC<<<gC, 256, 0, stream>>>(posedirs, shapedirs, v_template, ef,
                                        aadjT, weights, out);
    }
    smpl_kD<<<256, 256, 0, stream>>>(out, jointreg, out + OUT_JOINTS_OFF);
}

// Round 7
// 176.306 us; speedup vs baseline: 1.0983x; 1.0983x over previous
//
#include <hip/hip_runtime.h>
#include <math.h>

#define NV   6890
#define NJ   24
#define NB   10
#define NPF  207
#define NCJ  19
#define BATCHN 1024
#define NC3  (NV*3)     // 20670
#define KTOT 224        // 207 pose + 10 beta + 7 zero pad

#define OUT_JOINTS_OFF (BATCHN*NV*3)
#define OUT_RS_OFF     (OUT_JOINTS_OFF + BATCHN*NCJ*3)

// ws float offsets
#define WS_JS     0        // [24][33] f32
#define WS_EF     1024     // [1024][224] bf16
#define WS_AADJT  115712   // [1024][16][32] bf16
#define WS_JRB    377856   // [19][6890] bf16

typedef __attribute__((ext_vector_type(8))) short short8;
typedef __attribute__((ext_vector_type(4))) float f32x4;

__device__ __forceinline__ unsigned short f2bf(float f) {
    unsigned u = __float_as_uint(f);
    unsigned r = u + 0x7FFFu + ((u >> 16) & 1u);   // RNE
    return (unsigned short)(r >> 16);
}
__device__ __forceinline__ float bf2f(unsigned short u) {
    return __uint_as_float((unsigned)u << 16);
}

// ---------------- Kernel A: fold Jreg into dirs; convert joint_regressor --
__global__ void smpl_kA(const float* __restrict__ jreg, const float* __restrict__ sdirs,
                        const float* __restrict__ vtmpl, float* __restrict__ js,
                        const float* __restrict__ jointreg, unsigned short* __restrict__ jrb) {
    int tid = threadIdx.x;  // 256
    if (blockIdx.x >= NJ) {  // tail blocks: joint_regressor -> bf16
        int j = blockIdx.x - NJ;
        for (int v = tid; v < NV; v += 256)
            jrb[(size_t)j * NV + v] = f2bf(jointreg[(size_t)j * NV + v]);
        return;
    }
    int j = blockIdx.x;
    float acc[33];
#pragma unroll
    for (int e = 0; e < 33; e++) acc[e] = 0.f;
    for (int v = tid; v < NV; v += 256) {
        float w = jreg[j * NV + v];
#pragma unroll
        for (int k = 0; k < NB; k++) {
#pragma unroll
            for (int d = 0; d < 3; d++)
                acc[k * 3 + d] += w * sdirs[(size_t)k * NC3 + v * 3 + d];
        }
#pragma unroll
        for (int d = 0; d < 3; d++) acc[30 + d] += w * vtmpl[v * 3 + d];
    }
#pragma unroll
    for (int e = 0; e < 33; e++) {
#pragma unroll
        for (int off = 32; off >= 1; off >>= 1) acc[e] += __shfl_xor(acc[e], off, 64);
    }
    __shared__ float red[4][33];
    int lane = tid & 63, wv = tid >> 6;
    if (lane == 0) {
#pragma unroll
        for (int e = 0; e < 33; e++) red[wv][e] = acc[e];
    }
    __syncthreads();
    if (tid < 33) js[j * 33 + tid] = red[0][tid] + red[1][tid] + red[2][tid] + red[3][tid];
}

// ---------------- Kernel B: Rodrigues + chain + bf16 packs ----------------
__global__ void smpl_kB(const float* __restrict__ theta, const float* __restrict__ beta_,
                        const float* __restrict__ js, float* __restrict__ outRs,
                        unsigned short* __restrict__ ef, unsigned short* __restrict__ aadjT) {
    int b = blockIdx.x;
    int t = threadIdx.x;  // 64
    __shared__ float Rl[NJ][9];
    __shared__ float Jl[NJ][3];
    __shared__ float Rw[NJ][12];

    if (t < NJ) {
        int j = t;
        float tx = theta[b * 72 + j * 3 + 0];
        float ty = theta[b * 72 + j * 3 + 1];
        float tz = theta[b * 72 + j * 3 + 2];
        float ax = tx + 1e-8f, ay = ty + 1e-8f, az = tz + 1e-8f;
        float ang = sqrtf(ax * ax + ay * ay + az * az);
        float inv = 1.0f / ang;
        float rx = tx * inv, ry = ty * inv, rz = tz * inv;
        float s = sinf(ang), c = cosf(ang), t1 = 1.0f - c;
        float R[9];
        R[0] = 1.0f - t1 * (ry * ry + rz * rz);
        R[1] = -s * rz + t1 * rx * ry;
        R[2] =  s * ry + t1 * rx * rz;
        R[3] =  s * rz + t1 * rx * ry;
        R[4] = 1.0f - t1 * (rx * rx + rz * rz);
        R[5] = -s * rx + t1 * ry * rz;
        R[6] = -s * ry + t1 * rx * rz;
        R[7] =  s * rx + t1 * ry * rz;
        R[8] = 1.0f - t1 * (rx * rx + ry * ry);
#pragma unroll
        for (int e = 0; e < 9; e++) {
            Rl[j][e] = R[e];
            outRs[(size_t)b * 216 + j * 9 + e] = R[e];
        }
#pragma unroll
        for (int d = 0; d < 3; d++) {
            float accJ = js[j * 33 + 30 + d];
#pragma unroll
            for (int k = 0; k < NB; k++) accJ += beta_[b * NB + k] * js[j * 33 + k * 3 + d];
            Jl[j][d] = accJ;
        }
    }
    __syncthreads();
    for (int e = t; e < KTOT; e += 64) {
        float val;
        if (e < NPF) {
            int j = e / 9 + 1;
            int rc = e - (j - 1) * 9;
            val = Rl[j][rc] - ((rc == 0 || rc == 4 || rc == 8) ? 1.0f : 0.0f);
        } else if (e < NPF + NB) {
            val = beta_[b * NB + (e - NPF)];
        } else val = 0.f;
        ef[(size_t)b * KTOT + e] = f2bf(val);
    }
    if (t == 0) {
#pragma unroll
        for (int r = 0; r < 3; r++) {
            Rw[0][r * 4 + 0] =  Rl[0][r * 3 + 0];
            Rw[0][r * 4 + 1] = -Rl[0][r * 3 + 1];
            Rw[0][r * 4 + 2] = -Rl[0][r * 3 + 2];
            Rw[0][r * 4 + 3] =  Jl[0][r];
        }
        const int par[NJ] = {0,0,0,0,1,2,3,4,5,6,7,8,9,9,9,12,13,14,16,17,18,19,20,21};
#pragma unroll
        for (int i = 1; i < NJ; i++) {
            int p = par[i];
            float tr0 = Jl[i][0] - Jl[p][0];
            float tr1 = Jl[i][1] - Jl[p][1];
            float tr2 = Jl[i][2] - Jl[p][2];
#pragma unroll
            for (int r = 0; r < 3; r++) {
                float p0 = Rw[p][r * 4 + 0], p1 = Rw[p][r * 4 + 1], p2 = Rw[p][r * 4 + 2];
#pragma unroll
                for (int cc = 0; cc < 3; cc++)
                    Rw[i][r * 4 + cc] = p0 * Rl[i][0 + cc] + p1 * Rl[i][3 + cc] + p2 * Rl[i][6 + cc];
                Rw[i][r * 4 + 3] = p0 * tr0 + p1 * tr1 + p2 * tr2 + Rw[p][r * 4 + 3];
            }
        }
    }
    __syncthreads();
    // aadjT[b][n(16)][k(32)] bf16: n = row-major 3x4 index, k = joint
    for (int i = t; i < 512; i += 64) {
        int n = i >> 5, k = i & 31;
        float v = 0.f;
        if (n < 12 && k < 24) {
            int r = n >> 2, cc = n & 3;
            if (cc < 3) v = Rw[k][n];
            else v = Rw[k][r * 4 + 3] - (Rw[k][r * 4 + 0] * Jl[k][0] + Rw[k][r * 4 + 1] * Jl[k][1] +
                                         Rw[k][r * 4 + 2] * Jl[k][2]);
        }
        aadjT[(size_t)b * 512 + i] = f2bf(v);
    }
}

// ---------------- Kernel C4: LDS-dirs MFMA GEMM + MFMA T-blend, 8 waves ---
// block = 32 verts x 128 batches; grid (8 btgroups, 216 vtiles).
#define VPH(d, v, bl) ((d) * 4224 + (v) * 132 + (bl))
__global__ __launch_bounds__(512, 4) void smpl_kC4(
    const float* __restrict__ pdirs, const float* __restrict__ sdirs,
    const float* __restrict__ vtmpl, const unsigned short* __restrict__ ef,
    const unsigned short* __restrict__ aadjT, const float* __restrict__ wts,
    float* __restrict__ outv) {
    __shared__ unsigned short dl[21504];       // dirs frag-major: 42KB
    __shared__ unsigned short vph[3 * 4224];   // v_posed bf16 [d][v][bl(128+pad)]
    __shared__ unsigned short wbf[32][32];     // weights bf16 [v][k]

    int tid = threadIdx.x;
    int vtile = blockIdx.y;
    int btile = blockIdx.x * 128;
    int lane = tid & 63, wv = tid >> 6;
    int l15 = lane & 15, lg = lane >> 4;

    // stage dirs f32 -> bf16 fragment-major (coalesced reads, scattered LDS)
    for (int e = tid; e < KTOT * 96; e += 512) {
        int k = e / 96, c = e - k * 96;
        int gc = vtile * 96 + c;
        float val = 0.f;
        if (gc < NC3) {
            if (k < NPF) val = pdirs[(size_t)k * NC3 + gc];
            else if (k < NPF + NB) val = sdirs[(size_t)(k - NPF) * NC3 + gc];
        }
        dl[(((k >> 5) * 6 + (c >> 4)) << 9) + ((c & 15) << 5) + (k & 31)] = f2bf(val);
    }
    // stage weights bf16 [32 v][32 k]
    for (int e = tid; e < 1024; e += 512) {
        int vl = e >> 5, k = e & 31;
        int gv = vtile * 32 + vl;
        float w = (k < NJ && gv < NV) ? wts[(size_t)gv * NJ + k] : 0.f;
        wbf[vl][k] = f2bf(w);
    }
    __syncthreads();
    // after this barrier dl/wbf are read-only; vph use is wave-local.

    short8 wf0 = *(const short8*)&wbf[l15][lg * 8];
    short8 wf1 = *(const short8*)&wbf[16 + l15][lg * 8];
    float vt[6];
#pragma unroll
    for (int s = 0; s < 6; s++) {
        int gcol = vtile * 96 + s * 16 + l15;
        vt[s] = (gcol < NC3) ? vtmpl[gcol] : 0.f;
    }
    int fo = l15 * 4 + lg;

    // ---- pose+shape GEMM: 128 batches (16/wave) x 96 cols, K=224 ----
    const short8* efr = (const short8*)(ef + (size_t)(btile + wv * 16 + l15) * KTOT);
    short8 av[7];
#pragma unroll
    for (int ks = 0; ks < 7; ks++) av[ks] = efr[ks * 4 + lg];
    f32x4 acc[6];
#pragma unroll
    for (int s = 0; s < 6; s++) acc[s] = (f32x4){0.f, 0.f, 0.f, 0.f};
#pragma unroll
    for (int ks = 0; ks < 7; ks++) {
#pragma unroll
        for (int s = 0; s < 6; s++) {
            short8 bv = *(const short8*)&dl[((ks * 6 + s) << 9) + fo * 8];
            acc[s] = __builtin_amdgcn_mfma_f32_16x16x32_bf16(av[ks], bv, acc[s], 0, 0, 0);
        }
    }
    // ---- epilogue: vph = bf16(acc + v_template), wave-local, no barrier --
#pragma unroll
    for (int s = 0; s < 6; s++) {
        int col = s * 16 + l15;
        int v = col / 3, d = col - v * 3;
        int bl0 = wv * 16 + lg * 4;
        ushort4 pk;
        pk.x = f2bf(acc[s][0] + vt[s]);
        pk.y = f2bf(acc[s][1] + vt[s]);
        pk.z = f2bf(acc[s][2] + vt[s]);
        pk.w = f2bf(acc[s][3] + vt[s]);
        *(ushort4*)&vph[VPH(d, v, bl0)] = pk;
    }
    // ---- skinning: per-batch MFMA T-blend, 2-deep prefetch ----
    const short8* at0 = (const short8*)(aadjT + (size_t)(btile + wv * 16) * 512);
    short8 af0 = at0[fo];
    short8 af1 = at0[64 + fo];
#pragma unroll
    for (int bl2 = 0; bl2 < 16; bl2++) {
        short8 af = af0;
        af0 = af1;
        if (bl2 < 14) af1 = at0[(bl2 + 2) * 64 + fo];
        f32x4 z = (f32x4){0.f, 0.f, 0.f, 0.f};
        f32x4 t0 = __builtin_amdgcn_mfma_f32_16x16x32_bf16(af, wf0, z, 0, 0, 0);
        f32x4 t1 = __builtin_amdgcn_mfma_f32_16x16x32_bf16(af, wf1, z, 0, 0, 0);
        int b = btile + wv * 16 + bl2;
        int wvb = wv * 16 + bl2;
        if (lg < 3) {
            int p = lg;
            {
                int vv = l15;
                float x0 = bf2f(vph[VPH(0, vv, wvb)]);
                float x1 = bf2f(vph[VPH(1, vv, wvb)]);
                float x2 = bf2f(vph[VPH(2, vv, wvb)]);
                float o = fmaf(t0[0], x0, fmaf(t0[1], x1, fmaf(t0[2], x2, t0[3])));
                int gv = vtile * 32 + vv;
                if (gv < NV) outv[(size_t)b * NC3 + gv * 3 + p] = o;
            }
            {
                int vv = 16 + l15;
                float x0 = bf2f(vph[VPH(0, vv, wvb)]);
                float x1 = bf2f(vph[VPH(1, vv, wvb)]);
                float x2 = bf2f(vph[VPH(2, vv, wvb)]);
                float o = fmaf(t1[0], x0, fmaf(t1[1], x1, fmaf(t1[2], x2, t1[3])));
                int gv = vtile * 32 + vv;
                if (gv < NV) outv[(size_t)b * NC3 + gv * 3 + p] = o;
            }
        }
    }
}

// ---------------- Kernel D: COCO joint regression, 1 batch/block ----------
// 1024 blocks x 256 threads; vert-pairs, bf16 jr; wave+LDS reduce.
__global__ __launch_bounds__(256) void smpl_kD(
    const float* __restrict__ verts, const unsigned short* __restrict__ jrb,
    float* __restrict__ outj) {
    int tid = threadIdx.x;
    int b = blockIdx.x;
    const float* vb = verts + (size_t)b * NC3;
    float acc[57];
#pragma unroll
    for (int e = 0; e < 57; e++) acc[e] = 0.f;

    for (int it = 0; it < 14; it++) {
        int v2 = it * 256 + tid;     // pair index, 3445 pairs
        if (v2 < 3445) {
            int v = v2 * 2;
            const float* pa = vb + v * 3;
            float2 a0 = *(const float2*)(pa);      // x0 y0
            float2 a1 = *(const float2*)(pa + 2);  // z0 x1
            float2 a2 = *(const float2*)(pa + 4);  // y1 z1
#pragma unroll
            for (int j = 0; j < NCJ; j++) {
                unsigned wp = *(const unsigned*)(jrb + (size_t)j * NV + v);
                float w0 = __uint_as_float((wp & 0xFFFFu) << 16);
                float w1 = __uint_as_float(wp & 0xFFFF0000u);
                acc[j * 3 + 0] = fmaf(w0, a0.x, fmaf(w1, a1.y, acc[j * 3 + 0]));
                acc[j * 3 + 1] = fmaf(w0, a0.y, fmaf(w1, a2.x, acc[j * 3 + 1]));
                acc[j * 3 + 2] = fmaf(w0, a1.x, fmaf(w1, a2.y, acc[j * 3 + 2]));
            }
        }
    }
#pragma unroll
    for (int e = 0; e < 57; e++) {
#pragma unroll
        for (int off = 32; off >= 1; off >>= 1) acc[e] += __shfl_xor(acc[e], off, 64);
    }
    __shared__ float red[4][57];
    int lane = tid & 63, wv = tid >> 6;
    if (lane == 0) {
#pragma unroll
        for (int e = 0; e < 57; e++) red[wv][e] = acc[e];
    }
    __syncthreads();
    if (tid < 57)
        outj[(size_t)b * 57 + tid] = red[0][tid] + red[1][tid] + red[2][tid] + red[3][tid];
}

extern "C" void kernel_launch(void* const* d_in, const int* in_sizes, int n_in,
                              void* d_out, int out_size, void* d_ws, size_t ws_size,
                              hipStream_t stream) {
    (void)in_sizes; (void)n_in; (void)out_size; (void)ws_size;
    const float* beta       = (const float*)d_in[0];
    const float* theta      = (const float*)d_in[1];
    const float* v_template = (const float*)d_in[2];
    const float* shapedirs  = (const float*)d_in[3];
    const float* jreg       = (const float*)d_in[4];
    const float* posedirs   = (const float*)d_in[5];
    const float* jointreg   = (const float*)d_in[6];
    const float* weights    = (const float*)d_in[7];
    float* out = (float*)d_out;
    float* ws  = (float*)d_ws;
    unsigned short* ef    = (unsigned short*)(ws + WS_EF);
    unsigned short* aadjT = (unsigned short*)(ws + WS_AADJT);
    unsigned short* jrb   = (unsigned short*)(ws + WS_JRB);

    smpl_kA<<<NJ + NCJ, 256, 0, stream>>>(jreg, shapedirs, v_template, ws + WS_JS,
                                          jointreg, jrb);
    smpl_kB<<<BATCHN, 64, 0, stream>>>(theta, beta, ws + WS_JS, out + OUT_RS_OFF,
                                       ef, aadjT);
    dim3 gC(8, 216);
    smpl_kC4<<<gC, 512, 0, stream>>>(posedirs, shapedirs, v_template, ef,
                                     aadjT, weights, out);
    smpl_kD<<<BATCHN, 256, 0, stream>>>(out, jrb, out + OUT_JOINTS_OFF);
}